// Round 3
// baseline (278.937 us; speedup 1.0000x reference)
//
#include <hip/hip_runtime.h>

// SE_loss_w_threshold: h,v (8,16384,128) fp32, N scalar.
// out[0]=mean(Rp), out[1..8]=R_per_user_p, out[9]=sum(R_per_user_p)
//
// v4: occupancy 2x via half-k staging.
//   v1/v3 post-mortem: latency-bound on the DS pipe (64 ds_read_b128 +
//   shuffle chains per iteration, ~120cy each), with only 16 waves/CU
//   resident (LDS 34.3KB/block -> 4 blocks/CU) to hide it. VALUBusy 23%,
//   Occupancy 30%, both pipes idle.
//   Fix: stage k in TWO halves (8 rows x {re,im} x 32 floats per array),
//   carrying are/aim across halves in registers (k ascending 0..63 =>
//   A-matrix accumulation order identical to v1). Per-wave LDS halves ->
//   512-thread blocks at 37.2KB -> 4 blocks x 8 waves = 32 waves/CU.
//   __launch_bounds__(512,8) caps VGPR at 64 (v1/v3 used 52-60).
//   Register prefetch of the next half-tile retained (1 phase deep).
//   se_final rewritten: 1024 threads, deterministic wave-tree reduction
//   (old version: 256 threads + LDS atomicAdd, serial-ish and a possible
//   hidden cost in total dur).
// absmax: ~1e-6 expected (normsq lane partition + final tree reassoc;
// A/R accumulation orders unchanged).

constexpr int U_    = 8;
constexpr int B_    = 16384;
constexpr int NT_   = 128;
constexpr int NBLK_ = 1024;
constexpr int WPB_  = 8;              // waves per block (512 threads)
constexpr int TW_   = NBLK_ * WPB_;   // 8192 waves
constexpr int IT_   = B_ / TW_;       // 2 batches per wave
constexpr int RS_   = 36;             // LDS plane-row stride (floats): 16B-aligned, v1-like bank classes
constexpr float T_THRESH = 0.3f;
constexpr float LOG2_10  = 3.3219280948873623f;

__device__ __forceinline__ float waveReduceSum(float v) {
    #pragma unroll
    for (int m = 1; m < 64; m <<= 1) v += __shfl_xor(v, m, 64);
    return v;
}

__device__ __forceinline__ float hw_log2(float x) { return __builtin_amdgcn_logf(x); }
__device__ __forceinline__ float hw_exp2(float x) { return __builtin_amdgcn_exp2f(x); }

__global__ __launch_bounds__(512, 8) void se_main(const float* __restrict__ h,
                                                  const float* __restrict__ vv,
                                                  const float* __restrict__ Np,
                                                  float* __restrict__ partial) {
    // Per-wave PRIVATE half-k tiles: [16 plane-rows][RS_] per array.
    // plane-row = 2*user + {0:re,1:im}; 32 floats used + 4 pad.
    __shared__ float lds[WPB_][2][16 * RS_];
    __shared__ float red_f[WPB_];
    __shared__ float red_R[WPB_][U_];

    const int tid  = threadIdx.x;
    const int wave = tid >> 6;
    const int lane = tid & 63;
    const int ui   = lane >> 3;   // user i (row of A); also staging row
    const int uj   = lane & 7;    // user j (col of A); also staging float4-col
    const float Nval = Np[0];

    float* hb = lds[wave][0];
    float* vb = lds[wave][1];

    const int gwave = blockIdx.x * WPB_ + wave;

    // Per-lane global row base for staging: row = ui, float4-col = uj.
    const float* hrb = h  + (size_t)ui * ((size_t)B_ * NT_) + uj * 4;
    const float* vrb = vv + (size_t)ui * ((size_t)B_ * NT_) + uj * 4;

    float lane_sumR = 0.0f;
    float lane_sumf = 0.0f;

    float4 rh0, rh1, rv0, rv1;

    // ---- prologue: phase 0 = (batch gwave, k-half 0) ----
    {
        const int off = gwave * NT_;                  // x=0: re at [0,32), im at [64,96)
        rh0 = *reinterpret_cast<const float4*>(hrb + off);
        rh1 = *reinterpret_cast<const float4*>(hrb + off + 64);
        rv0 = *reinterpret_cast<const float4*>(vrb + off);
        rv1 = *reinterpret_cast<const float4*>(vrb + off + 64);
    }

    #pragma unroll
    for (int it = 0; it < IT_; ++it) {
        float nsq = 0.0f, are = 0.0f, aim = 0.0f;
        #pragma unroll
        for (int x = 0; x < 2; ++x) {
            // ---- drain regs -> LDS half-tile ----
            *reinterpret_cast<float4*>(&hb[(2 * ui + 0) * RS_ + uj * 4]) = rh0;
            *reinterpret_cast<float4*>(&hb[(2 * ui + 1) * RS_ + uj * 4]) = rh1;
            *reinterpret_cast<float4*>(&vb[(2 * ui + 0) * RS_ + uj * 4]) = rv0;
            *reinterpret_cast<float4*>(&vb[(2 * ui + 1) * RS_ + uj * 4]) = rv1;
            nsq += rv0.x * rv0.x + rv0.y * rv0.y + rv0.z * rv0.z + rv0.w * rv0.w
                 + rv1.x * rv1.x + rv1.y * rv1.y + rv1.z * rv1.z + rv1.w * rv1.w;

            // ---- prefetch next phase (next k-half or next batch) ----
            const int np = it * 2 + x + 1;
            if (np < 2 * IT_) {
                const int nb  = gwave + (np >> 1) * TW_;
                const int nx  = np & 1;
                const int off = nb * NT_ + nx * 32;
                rh0 = *reinterpret_cast<const float4*>(hrb + off);
                rh1 = *reinterpret_cast<const float4*>(hrb + off + 64);
                rv0 = *reinterpret_cast<const float4*>(vrb + off);
                rv1 = *reinterpret_cast<const float4*>(vrb + off + 64);
            }

            // ---- A[i][j] partial over this k-half (global k = x*32 + ks, ascending) ----
            const float* hre = &hb[(2 * ui) * RS_];
            const float* him = hre + RS_;
            const float* vre = &vb[(2 * uj) * RS_];
            const float* vim = vre + RS_;
            #pragma unroll
            for (int ks = 0; ks < 32; ks += 4) {
                const float4 hr = *reinterpret_cast<const float4*>(hre + ks);
                const float4 hi = *reinterpret_cast<const float4*>(him + ks);
                const float4 vr = *reinterpret_cast<const float4*>(vre + ks);
                const float4 vi = *reinterpret_cast<const float4*>(vim + ks);
                are += hr.x * vr.x + hi.x * vi.x;
                aim += hi.x * vr.x - hr.x * vi.x;
                are += hr.y * vr.y + hi.y * vi.y;
                aim += hi.y * vr.y - hr.y * vi.y;
                are += hr.z * vr.z + hi.z * vi.z;
                aim += hi.z * vr.z - hr.z * vi.z;
                are += hr.w * vr.w + hi.w * vi.w;
                aim += hi.w * vr.w - hr.w * vi.w;
            }
        }

        // ---- finish batch (identical to v1) ----
        const float normsq = waveReduceSum(nsq);
        const float Iall = are * are + aim * aim;

        const float diag = __shfl(Iall, ui * 9, 64);
        float rowsum = Iall;
        rowsum += __shfl_xor(rowsum, 1, 64);
        rowsum += __shfl_xor(rowsum, 2, 64);
        rowsum += __shfl_xor(rowsum, 4, 64);

        const float Ip   = rowsum - diag;
        const float S    = (8.0f / normsq) * diag;
        const float SINR = S / (Ip + Nval);
        const float R    = hw_log2(1.0f + SINR);

        lane_sumR += R;
        lane_sumf += hw_exp2((T_THRESH - R) * LOG2_10) - R;
    }

    // ---- block-level reduction ----
    const float wf = waveReduceSum(lane_sumf) * 0.125f;  // each user counted 8x
    if (lane == 0) red_f[wave] = wf;
    if (uj == 0)   red_R[wave][ui] = lane_sumR;
    __syncthreads();

    if (tid < U_) {
        float s = 0.0f;
        #pragma unroll
        for (int w = 0; w < WPB_; ++w) s += red_R[w][tid];
        partial[blockIdx.x * 9 + 1 + tid] = s;
    } else if (tid == U_) {
        float s = 0.0f;
        #pragma unroll
        for (int w = 0; w < WPB_; ++w) s += red_f[w];
        partial[blockIdx.x * 9] = s;
    }
}

__global__ __launch_bounds__(1024) void se_final(const float* __restrict__ partial,
                                                 float* __restrict__ out) {
    // 1024 threads: one partial-row each; deterministic wave trees + fixed
    // cross-wave order (no atomics, single pass).
    __shared__ float acc[16][9];
    const int tid = threadIdx.x, w = tid >> 6, l = tid & 63;

    float v[9];
    #pragma unroll
    for (int s = 0; s < 9; ++s) v[s] = partial[tid * 9 + s];

    #pragma unroll
    for (int s = 0; s < 9; ++s) {
        float t = v[s];
        #pragma unroll
        for (int m = 1; m < 64; m <<= 1) t += __shfl_xor(t, m, 64);
        if (l == 0) acc[w][s] = t;
    }
    __syncthreads();

    if (tid == 0) {
        float sums[9];
        #pragma unroll
        for (int s = 0; s < 9; ++s) {
            float t = acc[0][s];
            #pragma unroll
            for (int ww = 1; ww < 16; ++ww) t += acc[ww][s];
            sums[s] = t;
        }
        const float inv = 1.0f / (float)B_;
        out[0] = sums[0] * inv;          // mean(Rp)
        float tot = 0.0f;
        #pragma unroll
        for (int i = 0; i < U_; ++i) {
            const float r = sums[1 + i] * inv;
            out[1 + i] = r;              // R_per_user_p
            tot += r;
        }
        out[9] = tot;                    // sum(R_per_user_p)
    }
}

extern "C" void kernel_launch(void* const* d_in, const int* in_sizes, int n_in,
                              void* d_out, int out_size, void* d_ws, size_t ws_size,
                              hipStream_t stream) {
    const float* h  = (const float*)d_in[0];
    const float* v  = (const float*)d_in[1];
    const float* Np = (const float*)d_in[2];
    float* out      = (float*)d_out;
    float* partial  = (float*)d_ws;   // NBLK_*9 floats (36864 B), fully overwritten each call

    se_main<<<NBLK_, 512, 0, stream>>>(h, v, Np, partial);
    se_final<<<1, 1024, 0, stream>>>(partial, out);
}